// Round 13
// baseline (385.640 us; speedup 1.0000x reference)
//
#include <hip/hip_runtime.h>

typedef unsigned short u16;
typedef __attribute__((ext_vector_type(4))) float f32x4;
typedef __attribute__((ext_vector_type(8))) short s16x8;
typedef __attribute__((ext_vector_type(4))) short s16x4;

#define DEVI static __device__ __forceinline__

constexpr int S = 2048, HID = 1024, NH = 16, D = 256, INTER = 4096;

// ---------------- workspace layout (u16 elements) ----------------
constexpr size_t N_XB   = (size_t)S*HID;       // x bf16
constexpr size_t N_W    = (size_t)INTER*HID;   // Wg/Wu/Wd bf16
constexpr size_t N_WQK  = (size_t)NH*D*D;
constexpr size_t N_W1C  = (size_t)NH*D*768;    // folded W1 per head
constexpr size_t N_W2   = (size_t)D*D;
constexpr size_t N_COMB = (size_t)NH*S*768;    // [h | adj@h | attn_agg]
constexpr size_t N_HB   = (size_t)NH*S*D;      // h chunked (B-operand layout)

constexpr size_t O_XB   = 0;
constexpr size_t O_WG   = O_XB + N_XB;
constexpr size_t O_WU   = O_WG + N_W;
constexpr size_t O_WD   = O_WU + N_W;
constexpr size_t O_WQ   = O_WD + N_W;
constexpr size_t O_WK   = O_WQ + N_WQK;
constexpr size_t O_W1C  = O_WK + N_WQK;
constexpr size_t O_W2   = O_W1C + N_W1C;   // holds W2^T
constexpr size_t O_COMB = O_W2 + N_W2;
constexpr size_t O_HB   = O_COMB + N_COMB;
constexpr size_t O_QB   = O_HB + N_HB;   // Q  (later reused: u = silu(comb@W1cat^T), row-major s x INTER)
constexpr size_t O_KC   = O_QB + N_HB;   // Kc (later reused: Wfold = Wd_h @ W2, row-major 1024 x INTER)

// ---------------- helpers ----------------
DEVI u16 f2bf(float f) {
  union { float f; unsigned u; } v; v.f = f;
  unsigned r = v.u + 0x7FFFu + ((v.u >> 16) & 1u);
  return (u16)(r >> 16);
}

DEVI float bf2f(u16 b) {
  union { unsigned u; float f; } v; v.u = ((unsigned)b) << 16;
  return v.f;
}

DEVI void gload16(const void* g, const void* l) {
  __builtin_amdgcn_global_load_lds(
      (const __attribute__((address_space(1))) unsigned int*)g,
      (__attribute__((address_space(3))) unsigned int*)l, 16, 0, 0);
}

DEVI f32x4 ntload(const float* p) {
  return __builtin_nontemporal_load((const f32x4*)p);
}

// stage a 128-row x 32-k bf16 tile from row-major src into LDS chunked [k/8][row] (16B chunks)
DEVI void stage_rm(const u16* src, int stride, u16* lds, int tid) {
  const int wid = tid >> 6;
#pragma unroll
  for (int i = 0; i < 2; ++i) {
    int c = i * 256 + tid;                               // c = kp*128 + row
    gload16(src + (size_t)(c & 127) * stride + (c >> 7) * 8,
            lds + (size_t)(i * 256 + wid * 64) * 8);
  }
}

// stage a 64-row x 32-k tile, chunked [k/8][row64]
DEVI void stage_rm64(const u16* src, int stride, u16* lds, int tid) {
  const int wid = tid >> 6;
  gload16(src + (size_t)(tid & 63) * stride + (tid >> 6) * 8,
          lds + (size_t)(wid * 64) * 8);
}

DEVI s16x8 ldfrag(const u16* lds, int kp, int row) {
  return *(const s16x8*)(lds + ((size_t)kp * 128 + row) * 8);
}

DEVI s16x8 ldfrag64(const u16* lds, int kp, int row) {
  return *(const s16x8*)(lds + ((size_t)kp * 64 + row) * 8);
}

// ---------------- K1: convert weights/x to bf16 (vectorized), build W1cat, W2^T ----------------
__global__ void k_convert(const float* __restrict__ x,  const float* __restrict__ Wg,
                          const float* __restrict__ Wu, const float* __restrict__ Wd,
                          const float* __restrict__ Wq, const float* __restrict__ Wk,
                          const float* __restrict__ W1, const float* __restrict__ W2,
                          const float* __restrict__ eps, const float* __restrict__ alpha,
                          u16* __restrict__ ws) {
  // vectorized pure-convert segments (all counts are multiples of 4)
  const size_t totv = (N_XB + 3 * N_W + 2 * N_WQK) / 4;
  for (size_t vi = (size_t)blockIdx.x * blockDim.x + threadIdx.x; vi < totv;
       vi += (size_t)gridDim.x * blockDim.x) {
    size_t j = vi * 4;
    const float* src; size_t dst;
    if (j < N_XB)                { src = x  + j;                    dst = O_XB + j; }
    else if ((j -= N_XB) < N_W)  { src = Wg + j;                    dst = O_WG + j; }
    else if ((j -= N_W) < N_W)   { src = Wu + j;                    dst = O_WU + j; }
    else if ((j -= N_W) < N_W)   { src = Wd + j;                    dst = O_WD + j; }
    else if ((j -= N_W) < N_WQK) { src = Wq + j;                    dst = O_WQ + j; }
    else   { j -= N_WQK;           src = Wk + j;                    dst = O_WK + j; }
    f32x4 v = *(const f32x4*)src;
    s16x4 w;
    w[0] = (short)f2bf(v[0]); w[1] = (short)f2bf(v[1]);
    w[2] = (short)f2bf(v[2]); w[3] = (short)f2bf(v[3]);
    *(s16x4*)(ws + dst) = w;
  }
  // scalar tail: W2^T + folded W1cat
  const size_t tot2 = N_W2 + N_W1C;
  for (size_t i = (size_t)blockIdx.x * blockDim.x + threadIdx.x; i < tot2;
       i += (size_t)gridDim.x * blockDim.x) {
    size_t j = i;
    if (j < N_W2) { ws[O_W2 + j] = f2bf(W2[(j % D) * D + (j / D)]); continue; } j -= N_W2;
    size_t h = j / ((size_t)D * 768);
    size_t r = j % ((size_t)D * 768);
    size_t o = r / 768, c = r % 768;
    float v;
    if (c < 256)      v = (1.f + eps[h]) * W1[o * 1024 + c] + W1[o * 1024 + 512 + c];
    else if (c < 512) v = alpha[h] * W1[o * 1024 + c];
    else              v = W1[o * 1024 + 256 + c];
    ws[O_W1C + j] = f2bf(v);
  }
}

// ---------------- K2/K2b: dual GEMM sharing A (XCD-grouped, counted-vmcnt dbuf pipeline) ----------------
// MODE 0: g=x@Wg^T, u=x@Wu^T, h=silu(g)*u -> comb[:, :, 0:256] and hB (chunked). Grid 512 1-D.
// MODE 1: Q=h@Wq^T -> Qb; K=h@Wk^T -> Kc chunked. Grid 512 1-D, head-grouped per XCD.
template <int MODE>
__global__ __launch_bounds__(256, 2) void k_dual(const u16* __restrict__ Ab,
                                                 const u16* __restrict__ B0b,
                                                 const u16* __restrict__ B1b,
                                                 u16* __restrict__ o0, u16* __restrict__ o1) {
  __shared__ u16 lA[2][4096], lB0[2][4096], lB1[2][4096];   // 48 KB
  const int tid = threadIdx.x, lane = tid & 63, wid = tid >> 6;
  const int wm = wid >> 1, wn = wid & 1;
  int m0, nt, head;
  {
    const int bid = blockIdx.x, slot = bid & 7, j = bid >> 3;   // slot -> XCD
    if (MODE == 0) {
      nt   = slot * 4 + (j & 3);     // 4 B-panels per XCD (2 MB, L2-resident)
      m0   = (j >> 2) * 128;
      head = 0;
    } else {
      head = slot + 8 * (j >> 5);    // 2 heads per XCD
      const int rem = j & 31;
      nt   = rem & 1;
      m0   = (rem >> 1) * 128;
    }
  }

  const int K  = (MODE == 0) ? HID : D;
  const int sA = (MODE == 0) ? HID : 768;
  const int sB = (MODE == 0) ? HID : D;
  const u16* A  = (MODE == 0) ? (Ab + (size_t)m0 * HID)
                              : (Ab + ((size_t)head * S + m0) * 768);
  const u16* B0 = (MODE == 0) ? (B0b + (size_t)nt * 128 * HID)
                              : (B0b + (size_t)head * D * D + (size_t)nt * 128 * D);
  const u16* B1 = (MODE == 0) ? (B1b + (size_t)nt * 128 * HID)
                              : (B1b + (size_t)head * D * D + (size_t)nt * 128 * D);

  f32x4 a0[4][4], a1[4][4];
#pragma unroll
  for (int i = 0; i < 4; ++i)
#pragma unroll
    for (int j2 = 0; j2 < 4; ++j2) { a0[i][j2] = f32x4{0.f,0.f,0.f,0.f}; a1[i][j2] = f32x4{0.f,0.f,0.f,0.f}; }

  auto STAGE = [&](int k0, int cur) {
    stage_rm(A  + k0, sA, &lA[cur][0],  tid);
    stage_rm(B0 + k0, sB, &lB0[cur][0], tid);
    stage_rm(B1 + k0, sB, &lB1[cur][0], tid);
  };
  auto STEP = [&](int k0, int cur) {
    const int k1 = (k0 + 32 < K) ? k0 + 32 : k0;   // clamp: constant vmem count
    STAGE(k1, cur ^ 1);                             // tile k+1 into other buffer
    // tile k's 6 loads (issued last step) done; tile k+1's 6 stay in flight
    asm volatile("s_waitcnt vmcnt(6)" ::: "memory");
    __builtin_amdgcn_s_barrier();
    __builtin_amdgcn_sched_barrier(0);
    const int kp = lane >> 4, r = lane & 15;
    s16x8 af[4], b0f[4], b1f[4];
#pragma unroll
    for (int f = 0; f < 4; ++f) {
      af[f]  = ldfrag(&lA[cur][0],  kp, wm * 64 + f * 16 + r);
      b0f[f] = ldfrag(&lB0[cur][0], kp, wn * 64 + f * 16 + r);
      b1f[f] = ldfrag(&lB1[cur][0], kp, wn * 64 + f * 16 + r);
    }
#pragma unroll
    for (int fi = 0; fi < 4; ++fi)
#pragma unroll
      for (int fj = 0; fj < 4; ++fj) {
        a0[fi][fj] = __builtin_amdgcn_mfma_f32_16x16x32_bf16(af[fi], b0f[fj], a0[fi][fj], 0, 0, 0);
        a1[fi][fj] = __builtin_amdgcn_mfma_f32_16x16x32_bf16(af[fi], b1f[fj], a1[fi][fj], 0, 0, 0);
      }
    // all waves done reading buf[cur] before next step overwrites it
    __builtin_amdgcn_sched_barrier(0);
    __builtin_amdgcn_s_barrier();
  };

  STAGE(0, 0);
  for (int k0 = 0; k0 < K; k0 += 64) { STEP(k0, 0); STEP(k0 + 32, 1); }
  asm volatile("s_waitcnt vmcnt(0)" ::: "memory");

#pragma unroll
  for (int fi = 0; fi < 4; ++fi)
#pragma unroll
    for (int fj = 0; fj < 4; ++fj)
#pragma unroll
      for (int reg = 0; reg < 4; ++reg) {
        int row = m0 + wm * 64 + fi * 16 + ((lane >> 4) * 4 + reg);
        int cl  = wn * 64 + fj * 16 + (lane & 15);
        if (MODE == 0) {
          int col = nt * 128 + cl;
          float g = a0[fi][fj][reg], uu = a1[fi][fj][reg];
          float h = g / (1.f + __expf(-g)) * uu;   // silu(g)*u
          u16 hb = f2bf(h);
          int hh = col >> 8, d = col & 255;
          o0[((size_t)hh * S + row) * 768 + d] = hb;                               // comb h-part
          o1[(((size_t)hh * (S / 8) + (row >> 3)) * 256 + d) * 8 + (row & 7)] = hb; // hB chunked
        } else {
          int e = nt * 128 + cl;
          o0[((size_t)head * S + row) * D + e] = f2bf(a0[fi][fj][reg]);            // Q row-major
          o1[(((size_t)head * 32 + (e >> 3)) * S + row) * 8 + (e & 7)] = f2bf(a1[fi][fj][reg]); // Kc chunked
        }
      }
}

// ---------------- K3: fused flash attention (multiplicative adj mask) + sum_agg ----------------
// Round-10 core: double-buffered staging, counted vmcnt(10), head->XCD-grouped grid,
// non-temporal adjacency loads.
__global__ __launch_bounds__(256, 2) void k_attn(const float* __restrict__ adj,
                                                 const u16* __restrict__ Qb,
                                                 const u16* __restrict__ Kc,
                                                 const u16* __restrict__ hB,
                                                 u16* __restrict__ comb) {
  __shared__ u16 lK[2][1024 * 8];   // [e8:32][t:32] 16B chunks, 16KB each
  __shared__ u16 lH[2][1024 * 8];   // [t8:4][d:256] 16B chunks, 16KB each
  __shared__ u16 lAdj[2][64 * 36];  // [q:64][t:32 pad 36], 4.5KB each
  __shared__ u16 lP[4][16 * 36];    // per-wave P transpose, 4.5KB
  const int tid = threadIdx.x, lane = tid & 63, wid = tid >> 6;
  // head->XCD grouping: bid%8 selects a head-group slot; each XCD serves heads {s, s+8}
  const int bid  = blockIdx.x;
  const int slot = bid & 7;
  const int idx  = bid >> 3;          // 0..63
  const int head = slot + 8 * (idx >> 5);
  const int bx   = idx & 31;
  const int q0 = bx * 64 + wid * 16;
  const int l15 = lane & 15, l4 = lane >> 4;

  s16x8 q[8];
  {
    const u16* qr = Qb + ((size_t)head * S + q0 + l15) * D + l4 * 8;
#pragma unroll
    for (int ks = 0; ks < 8; ++ks) q[ks] = *(const s16x8*)(qr + ks * 32);
  }
  f32x4 accO[16], accS[16];
#pragma unroll
  for (int i = 0; i < 16; ++i) { accO[i] = f32x4{0.f,0.f,0.f,0.f}; accS[i] = f32x4{0.f,0.f,0.f,0.f}; }
  float m_r[4] = {-1e30f, -1e30f, -1e30f, -1e30f};
  float l_r[4] = {0.f, 0.f, 0.f, 0.f};   // per-lane partial denominators

  const float* adjB = adj + ((size_t)head * S + bx * 64) * S;
  const int arow = tid >> 3;          // 0..31
  const int acol = (tid & 7) * 4;     // 0,4,..,28

  // prologue: stage tile 0 (K,H) into buf0 + prefetch adjacency tile 0 to regs
#pragma unroll
  for (int i = 0; i < 4; ++i) {
    int c = i * 256 + tid;
    gload16(Kc + ((size_t)(head * 32 + (c >> 5)) * S + (c & 31)) * 8,
            &lK[0][(size_t)(i * 256 + wid * 64) * 8]);
  }
#pragma unroll
  for (int i = 0; i < 4; ++i) {
    int c = i * 256 + tid;
    gload16(hB + ((size_t)(head * (S / 8) + (c >> 8)) * 256 + (c & 255)) * 8,
            &lH[0][(size_t)(i * 256 + wid * 64) * 8]);
  }
  f32x4 av0 = ntload(adjB + (size_t)arow * S + acol);
  f32x4 av1 = ntload(adjB + (size_t)(arow + 32) * S + acol);

  auto TILE = [&](int t0, int cur) {
    const int t1 = (t0 + 32 < S) ? t0 + 32 : t0;   // clamp: constant vmem count every iter
    // --- issue stage of tile t+1 into buf[cur^1] (8 gload_lds) ---
#pragma unroll
    for (int i = 0; i < 4; ++i) {
      int c = i * 256 + tid;
      gload16(Kc + ((size_t)(head * 32 + (c >> 5)) * S + t1 + (c & 31)) * 8,
              &lK[cur ^ 1][(size_t)(i * 256 + wid * 64) * 8]);
    }
#pragma unroll
    for (int i = 0; i < 4; ++i) {
      int c = i * 256 + tid;
      gload16(hB + ((size_t)(head * (S / 8) + (t1 >> 3) + (c >> 8)) * 256 + (c & 255)) * 8,
              &lH[cur ^ 1][(size_t)(i * 256 + wid * 64) * 8]);
    }
    // --- prefetch adjacency tile t+1 to regs (2 non-temporal loads) ---
    f32x4 nv0 = ntload(adjB + (size_t)arow * S + t1 + acol);
    f32x4 nv1 = ntload(adjB + (size_t)(arow + 32) * S + t1 + acol);
    // --- write adjacency tile t (regs) to lAdj[cur] as bf16 ---
    {
      s16x4 w;
      w[0] = (short)f2bf(av0[0]); w[1] = (short)f2bf(av0[1]);
      w[2] = (short)f2bf(av0[2]); w[3] = (short)f2bf(av0[3]);
      *(s16x4*)(&lAdj[cur][(size_t)arow * 36 + acol]) = w;
      w[0] = (short)f2bf(av1[0]); w[1] = (short)f2bf(av1[1]);
      w[2] = (short)f2bf(av1[2]); w[3] = (short)f2bf(av1[3]);
      *(s16x4*)(&lAdj[cur][(size_t)(arow + 32) * 36 + acol]) = w;
    }
    // wait: tile t's 10 vmem ops done (t+1's 10 stay in flight); lAdj writes done.
    asm volatile("s_waitcnt vmcnt(10) lgkmcnt(0)" ::: "memory");
    __builtin_amdgcn_s_barrier();
    __builtin_amdgcn_sched_barrier(0);

    const u16* lKc = &lK[cur][0];
    const u16* lHc = &lH[cur][0];
    const u16* lAc = &lAdj[cur][0];

    // QK^T (16 MFMA, 4 independent accumulator chains of depth 4)
    f32x4 scA[2], scB[2];
    scA[0] = f32x4{0.f,0.f,0.f,0.f}; scA[1] = f32x4{0.f,0.f,0.f,0.f};
    scB[0] = f32x4{0.f,0.f,0.f,0.f}; scB[1] = f32x4{0.f,0.f,0.f,0.f};
#pragma unroll
    for (int ks = 0; ks < 4; ++ks)
#pragma unroll
      for (int fj = 0; fj < 2; ++fj) {
        s16x8 b0 = *(const s16x8*)(lKc + ((size_t)(ks * 4 + l4) * 32 + fj * 16 + l15) * 8);
        s16x8 b1 = *(const s16x8*)(lKc + ((size_t)((ks + 4) * 4 + l4) * 32 + fj * 16 + l15) * 8);
        scA[fj] = __builtin_amdgcn_mfma_f32_16x16x32_bf16(q[ks], b0, scA[fj], 0, 0, 0);
        scB[fj] = __builtin_amdgcn_mfma_f32_16x16x32_bf16(q[ks + 4], b1, scB[fj], 0, 0, 0);
      }

    // mask values from lAdj (D-layout scalar reads)
    float av[2][4];
#pragma unroll
    for (int fj = 0; fj < 2; ++fj)
#pragma unroll
      for (int reg = 0; reg < 4; ++reg)
        av[fj][reg] = bf2f(lAc[(size_t)(wid * 16 + l4 * 4 + reg) * 36 + fj * 16 + l15]);

    float sf[2][4];
#pragma unroll
    for (int fj = 0; fj < 2; ++fj)
#pragma unroll
      for (int reg = 0; reg < 4; ++reg)
        sf[fj][reg] = (scA[fj][reg] + scB[fj][reg]) * 0.0625f;

    // defer-max: only reduce + rescale when some score exceeds m_r + 8
    bool chg = false;
    float lmax[4];
#pragma unroll
    for (int reg = 0; reg < 4; ++reg) {
      lmax[reg] = fmaxf(sf[0][reg], sf[1][reg]);
      chg |= (lmax[reg] > m_r[reg] + 8.f);
    }
    if (__any((int)chg)) {
      float scl[4];
#pragma unroll
      for (int reg = 0; reg < 4; ++reg) {
        float m = lmax[reg];
#pragma unroll
        for (int off = 1; off < 16; off <<= 1) m = fmaxf(m, __shfl_xor(m, off));
        float mn = fmaxf(m_r[reg], m);
        scl[reg] = __expf(m_r[reg] - mn);
        m_r[reg] = mn;
        l_r[reg] *= scl[reg];
      }
#pragma unroll
      for (int nf = 0; nf < 16; ++nf) {
        f32x4 t = accO[nf];
        t[0] *= scl[0]; t[1] *= scl[1]; t[2] *= scl[2]; t[3] *= scl[3];
        accO[nf] = t;
      }
    }
    u16 pb[2][4];
#pragma unroll
    for (int fj = 0; fj < 2; ++fj)
#pragma unroll
      for (int reg = 0; reg < 4; ++reg) {
        float p = (av[fj][reg] + 1e-9f) * exp2f((sf[fj][reg] - m_r[reg]) * 1.44269504f);
        l_r[reg] += p;                       // per-lane partial denominator
        pb[fj][reg] = f2bf(p);
      }

    // P: D-layout -> A-frag layout via wave-private LDS
    u16* pl = &lP[wid][0];
#pragma unroll
    for (int fj = 0; fj < 2; ++fj)
#pragma unroll
      for (int reg = 0; reg < 4; ++reg)
        pl[(size_t)(l4 * 4 + reg) * 36 + fj * 16 + l15] = pb[fj][reg];
    asm volatile("s_waitcnt lgkmcnt(0)" ::: "memory");
    __builtin_amdgcn_sched_barrier(0);

    s16x8 pa, aa;
    {
      s16x4 plo = *(const s16x4*)(pl + (size_t)l15 * 36 + l4 * 8);
      s16x4 phi = *(const s16x4*)(pl + (size_t)l15 * 36 + l4 * 8 + 4);
      pa[0] = plo[0]; pa[1] = plo[1]; pa[2] = plo[2]; pa[3] = plo[3];
      pa[4] = phi[0]; pa[5] = phi[1]; pa[6] = phi[2]; pa[7] = phi[3];
      s16x4 alo = *(const s16x4*)(lAc + (size_t)(wid * 16 + l15) * 36 + l4 * 8);
      s16x4 ahi = *(const s16x4*)(lAc + (size_t)(wid * 16 + l15) * 36 + l4 * 8 + 4);
      aa[0] = alo[0]; aa[1] = alo[1]; aa[2] = alo[2]; aa[3] = alo[3];
      aa[4] = ahi[0]; aa[5] = ahi[1]; aa[6] = ahi[2]; aa[7] = ahi[3];
    }
    // PV + sum_agg (32 MFMA) sharing lH fragment reads
#pragma unroll
    for (int nf = 0; nf < 16; ++nf) {
      s16x8 hb = *(const s16x8*)(lHc + ((size_t)l4 * 256 + nf * 16 + l15) * 8);
      accO[nf] = __builtin_amdgcn_mfma_f32_16x16x32_bf16(pa, hb, accO[nf], 0, 0, 0);
      accS[nf] = __builtin_amdgcn_mfma_f32_16x16x32_bf16(aa, hb, accS[nf], 0, 0, 0);
    }

    av0 = nv0; av1 = nv1;

    // end barrier: all waves done reading buf[cur] before next tile stages into it.
    __builtin_amdgcn_sched_barrier(0);
    __builtin_amdgcn_s_barrier();
  };

  for (int t0 = 0; t0 < S; t0 += 64) {
    TILE(t0, 0);
    TILE(t0 + 32, 1);
  }

  // drain in-flight gload_lds before workgroup can exit
  asm volatile("s_waitcnt vmcnt(0)" ::: "memory");

  // epilogue: reduce per-lane denominators across the 16 lanes of each q-row
#pragma unroll
  for (int reg = 0; reg < 4; ++reg) {
#pragma unroll
    for (int off = 1; off < 16; off <<= 1) l_r[reg] += __shfl_xor(l_r[reg], off);
  }
  float inv[4];
#pragma unroll
  for (int reg = 0; reg < 4; ++reg) inv[reg] = 1.f / l_r[reg];
#pragma unroll
  for (int nf = 0; nf < 16; ++nf)
#pragma unroll
    for (int reg = 0; reg < 4; ++reg) {
      size_t rb = ((size_t)head * S + q0 + l4 * 4 + reg) * 768;
      comb[rb + 512 + nf * 16 + l15] = f2bf(accO[nf][reg] * inv[reg]);
      comb[rb + 256 + nf * 16 + l15] = f2bf(accS[nf][reg]);
    }
}

// ---------------- K4/K5/K6: single-B GEMMs (XCD-grouped, counted-vmcnt dbuf pipeline) ----------------
// MODE 0: u = silu(comb @ W1cat^T) per head    -> oU[s][head*256+e] (BN=128, 1-D 512, head-grouped)
// MODE 3: Wfold_h = Wd_h @ W2 (B = W2^T)       -> oU[o][head*256+c] (BN=128, 3-D grid)
// MODE 2: out = u @ Wfold^T                    -> oF[s][1024] f32   (BN=64, 1-D 256, nt-grouped)
template <int MODE>
__global__ __launch_bounds__(256, 2) void k_gemm(const u16* __restrict__ Ab,
                                                 const u16* __restrict__ Bb,
                                                 u16* __restrict__ oU, float* __restrict__ oF) {
  constexpr int BN = (MODE == 2) ? 64 : 128;
  constexpr int FJ = BN / 32;            // frags per wave in N
  constexpr int NLD = 2 + ((BN == 128) ? 2 : 1);   // gloads per K-step
  __shared__ u16 lA[2][4096], lB[2][BN * 32];
  const int tid = threadIdx.x, lane = tid & 63, wid = tid >> 6;
  const int wm = wid >> 1, wn = wid & 1;
  int m0, nt, head;
  if constexpr (MODE == 0) {
    const int bid = blockIdx.x, slot = bid & 7, j = bid >> 3;
    head = slot + 8 * (j >> 5);          // 2 heads per XCD (B = 768KB, L2-resident)
    const int rem = j & 31;
    nt   = rem & 1;
    m0   = (rem >> 1) * 128;
  } else if constexpr (MODE == 2) {
    const int bid = blockIdx.x, slot = bid & 7, j = bid >> 3;
    nt   = slot * 2 + (j & 1);           // 2 B-panels per XCD (1 MB, L2-resident)
    m0   = (j >> 1) * 128;
    head = 0;
  } else {
    m0 = blockIdx.x * 128; nt = blockIdx.y; head = blockIdx.z;
  }

  constexpr int K  = (MODE == 0) ? 768 : (MODE == 2) ? INTER : D;
  constexpr int sA = (MODE == 3) ? INTER : K;
  constexpr int sB = K;
  const u16* A = (MODE == 0) ? Ab + ((size_t)head * S + m0) * 768
               : (MODE == 2) ? Ab + (size_t)m0 * INTER
                             : Ab + (size_t)m0 * INTER + head * D;
  const u16* B = (MODE == 0) ? Bb + ((size_t)head * D + nt * 128) * 768
                             : Bb + (size_t)nt * BN * sB;

  f32x4 acc[4][FJ];
#pragma unroll
  for (int i = 0; i < 4; ++i)
#pragma unroll
    for (int j = 0; j < FJ; ++j) acc[i][j] = f32x4{0.f,0.f,0.f,0.f};

  auto STAGE = [&](int k0, int cur) {
    stage_rm(A + k0, sA, &lA[cur][0], tid);
    if constexpr (BN == 128) stage_rm(B + k0, sB, &lB[cur][0], tid);
    else                     stage_rm64(B + k0, sB, &lB[cur][0], tid);
  };
  auto STEP = [&](int k0, int cur) {
    const int k1 = (k0 + 32 < K) ? k0 + 32 : k0;   // clamp: constant vmem count
    STAGE(k1, cur ^ 1);
    // tile k's NLD loads done; tile k+1's NLD stay in flight
    if constexpr (NLD == 4) asm volatile("s_waitcnt vmcnt(4)" ::: "memory");
    else                    asm volatile("s_waitcnt vmcnt(3)" ::: "memory");
    __builtin_amdgcn_s_barrier();
    __builtin_amdgcn_sched_barrier(0);
    const int kp = lane >> 4, r = lane & 15;
    s16x8 af[4], bf[FJ];
#pragma unroll
    for (int f = 0; f < 4; ++f) af[f] = ldfrag(&lA[cur][0], kp, wm * 64 + f * 16 + r);
#pragma unroll
    for (int f = 0; f < FJ; ++f) {
      if constexpr (BN == 128) bf[f] = ldfrag(&lB[cur][0], kp, wn * 64 + f * 16 + r);
      else                     bf[f] = ldfrag64(&lB[cur][0], kp, wn * 32 + f * 16 + r);
    }
#pragma unroll
    for (int fi = 0; fi < 4; ++fi)
#pragma unroll
      for (int fj = 0; fj < FJ; ++fj)
        acc[fi][fj] = __builtin_amdgcn_mfma_f32_16x16x32_bf16(af[fi], bf[fj], acc[fi][fj], 0, 0, 0);
    __builtin_amdgcn_sched_barrier(0);
    __builtin_amdgcn_s_barrier();
  };

  STAGE(0, 0);
  for (int k0 = 0; k0 < K; k0 += 64) { STEP(k0, 0); STEP(k0 + 32, 1); }
  asm volatile("s_waitcnt vmcnt(0)" ::: "memory");

#pragma unroll
  for (int fi = 0; fi < 4; ++fi)
#pragma unroll
    for (int fj = 0; fj < FJ; ++fj)
#pragma unroll
      for (int reg = 0; reg < 4; ++reg) {
        int row = m0 + wm * 64 + fi * 16 + ((lane >> 4) * 4 + reg);
        int cn = nt * BN + wn * (BN / 2) + fj * 16 + (lane & 15);
        float v = acc[fi][fj][reg];
        if (MODE == 0) {
          v = v / (1.f + __expf(-v));
          oU[(size_t)row * INTER + head * D + cn] = f2bf(v);
        } else if (MODE == 3) {
          oU[(size_t)row * INTER + head * D + cn] = f2bf(v);
        } else {
          oF[(size_t)row * HID + cn] = v;
        }
      }
}

// ---------------- launch ----------------
extern "C" void kernel_launch(void* const* d_in, const int* in_sizes, int n_in,
                              void* d_out, int out_size, void* d_ws, size_t ws_size,
                              hipStream_t stream) {
  const float* x     = (const float*)d_in[0];
  const float* adj   = (const float*)d_in[1];
  const float* Wg    = (const float*)d_in[2];
  const float* Wu    = (const float*)d_in[3];
  const float* Wd    = (const float*)d_in[4];
  const float* eps   = (const float*)d_in[5];
  const float* alpha = (const float*)d_in[6];
  const float* Wq    = (const float*)d_in[7];
  const float* Wk    = (const float*)d_in[8];
  const float* W1    = (const float*)d_in[9];
  const float* W2    = (const float*)d_in[10];
  u16* ws = (u16*)d_ws;

  k_convert<<<dim3(4096), dim3(256), 0, stream>>>(x, Wg, Wu, Wd, Wq, Wk, W1, W2, eps, alpha, ws);
  // 1-D grids, XCD-grouped decode inside kernels
  k_dual<0><<<dim3(512), dim3(256), 0, stream>>>(ws + O_XB, ws + O_WG, ws + O_WU,
                                                 ws + O_COMB, ws + O_HB);
  k_dual<1><<<dim3(512), dim3(256), 0, stream>>>(ws + O_COMB, ws + O_WQ, ws + O_WK,
                                                 ws + O_QB, ws + O_KC);
  k_attn<<<dim3(512), dim3(256), 0, stream>>>(adj, ws + O_QB, ws + O_KC, ws + O_HB, ws + O_COMB);
  // Wfold = Wd_h @ W2 (O_KC is free after k_attn)
  k_gemm<3><<<dim3(8, 2, 16), dim3(256), 0, stream>>>(ws + O_WD, ws + O_W2, ws + O_KC, nullptr);
  // u = silu(comb @ W1cat^T), head-grouped 1-D grid
  k_gemm<0><<<dim3(512), dim3(256), 0, stream>>>(ws + O_COMB, ws + O_W1C, ws + O_QB, nullptr);
  // out = u @ Wfold^T (BN=64, nt-grouped 1-D grid)
  k_gemm<2><<<dim3(256), dim3(256), 0, stream>>>(ws + O_QB, ws + O_KC, nullptr, (float*)d_out);
}

// Round 14
// 379.310 us; speedup vs baseline: 1.0167x; 1.0167x over previous
//
#include <hip/hip_runtime.h>

typedef unsigned short u16;
typedef __attribute__((ext_vector_type(4))) float f32x4;
typedef __attribute__((ext_vector_type(8))) short s16x8;
typedef __attribute__((ext_vector_type(4))) short s16x4;

#define DEVI static __device__ __forceinline__

constexpr int S = 2048, HID = 1024, NH = 16, D = 256, INTER = 4096;

// ---------------- workspace layout (u16 elements) ----------------
constexpr size_t N_XB   = (size_t)S*HID;       // x bf16
constexpr size_t N_W    = (size_t)INTER*HID;   // Wg/Wu/Wd bf16
constexpr size_t N_WQK  = (size_t)NH*D*D;
constexpr size_t N_W1C  = (size_t)NH*D*768;    // folded W1 per head
constexpr size_t N_W2   = (size_t)D*D;
constexpr size_t N_COMB = (size_t)NH*S*768;    // [h | adj@h | attn_agg]
constexpr size_t N_HB   = (size_t)NH*S*D;      // h chunked (B-operand layout)

constexpr size_t O_XB   = 0;
constexpr size_t O_WG   = O_XB + N_XB;
constexpr size_t O_WU   = O_WG + N_W;
constexpr size_t O_WD   = O_WU + N_W;
constexpr size_t O_WQ   = O_WD + N_W;
constexpr size_t O_WK   = O_WQ + N_WQK;
constexpr size_t O_W1C  = O_WK + N_WQK;
constexpr size_t O_W2   = O_W1C + N_W1C;   // holds W2^T
constexpr size_t O_COMB = O_W2 + N_W2;
constexpr size_t O_HB   = O_COMB + N_COMB;
constexpr size_t O_QB   = O_HB + N_HB;   // Q  (later reused: u = silu(comb@W1cat^T), row-major s x INTER)
constexpr size_t O_KC   = O_QB + N_HB;   // Kc (later reused: Wfold = Wd_h @ W2, row-major 1024 x INTER)

// ---------------- helpers ----------------
DEVI u16 f2bf(float f) {
  union { float f; unsigned u; } v; v.f = f;
  unsigned r = v.u + 0x7FFFu + ((v.u >> 16) & 1u);
  return (u16)(r >> 16);
}

DEVI float bf2f(u16 b) {
  union { unsigned u; float f; } v; v.u = ((unsigned)b) << 16;
  return v.f;
}

DEVI void gload16(const void* g, const void* l) {
  __builtin_amdgcn_global_load_lds(
      (const __attribute__((address_space(1))) unsigned int*)g,
      (__attribute__((address_space(3))) unsigned int*)l, 16, 0, 0);
}

DEVI f32x4 ntload(const float* p) {
  return __builtin_nontemporal_load((const f32x4*)p);
}

// stage a 128-row x 32-k bf16 tile from row-major src into LDS chunked [k/8][row] (16B chunks)
DEVI void stage_rm(const u16* src, int stride, u16* lds, int tid) {
  const int wid = tid >> 6;
#pragma unroll
  for (int i = 0; i < 2; ++i) {
    int c = i * 256 + tid;                               // c = kp*128 + row
    gload16(src + (size_t)(c & 127) * stride + (c >> 7) * 8,
            lds + (size_t)(i * 256 + wid * 64) * 8);
  }
}

// stage a 64-row x 32-k tile, chunked [k/8][row64]
DEVI void stage_rm64(const u16* src, int stride, u16* lds, int tid) {
  const int wid = tid >> 6;
  gload16(src + (size_t)(tid & 63) * stride + (tid >> 6) * 8,
          lds + (size_t)(wid * 64) * 8);
}

DEVI s16x8 ldfrag(const u16* lds, int kp, int row) {
  return *(const s16x8*)(lds + ((size_t)kp * 128 + row) * 8);
}

DEVI s16x8 ldfrag64(const u16* lds, int kp, int row) {
  return *(const s16x8*)(lds + ((size_t)kp * 64 + row) * 8);
}

// ---------------- K1: convert weights/x to bf16 (vectorized), build W1cat (row-decoded), W2^T ----------------
__global__ void k_convert(const float* __restrict__ x,  const float* __restrict__ Wg,
                          const float* __restrict__ Wu, const float* __restrict__ Wd,
                          const float* __restrict__ Wq, const float* __restrict__ Wk,
                          const float* __restrict__ W1, const float* __restrict__ W2,
                          const float* __restrict__ eps, const float* __restrict__ alpha,
                          u16* __restrict__ ws) {
  // vectorized pure-convert segments (all counts are multiples of 4)
  const size_t totv = (N_XB + 3 * N_W + 2 * N_WQK) / 4;
  for (size_t vi = (size_t)blockIdx.x * blockDim.x + threadIdx.x; vi < totv;
       vi += (size_t)gridDim.x * blockDim.x) {
    size_t j = vi * 4;
    const float* src; size_t dst;
    if (j < N_XB)                { src = x  + j;                    dst = O_XB + j; }
    else if ((j -= N_XB) < N_W)  { src = Wg + j;                    dst = O_WG + j; }
    else if ((j -= N_W) < N_W)   { src = Wu + j;                    dst = O_WU + j; }
    else if ((j -= N_W) < N_W)   { src = Wd + j;                    dst = O_WD + j; }
    else if ((j -= N_W) < N_WQK) { src = Wq + j;                    dst = O_WQ + j; }
    else   { j -= N_WQK;           src = Wk + j;                    dst = O_WK + j; }
    f32x4 v = *(const f32x4*)src;
    s16x4 w;
    w[0] = (short)f2bf(v[0]); w[1] = (short)f2bf(v[1]);
    w[2] = (short)f2bf(v[2]); w[3] = (short)f2bf(v[3]);
    *(s16x4*)(ws + dst) = w;
  }
  // W2^T (pow2 decode: cheap)
  for (size_t j = (size_t)blockIdx.x * blockDim.x + threadIdx.x; j < N_W2;
       j += (size_t)gridDim.x * blockDim.x)
    ws[O_W2 + j] = f2bf(W2[(j & 255) * D + (j >> 8)]);
  // W1cat: row-decoded, no division. 4096 rows (h=rid>>8, o=rid&255), 768 cols each:
  //   [0:256)   = (1+eps_h)*W1[o][c] + W1[o][512+c]
  //   [256:512) = alpha_h * W1[o][256+c]
  //   [512:768) = W1[o][768+c]
  const int t = threadIdx.x;            // 0..255
  for (int rid = blockIdx.x; rid < NH * D; rid += gridDim.x) {
    const int h = rid >> 8, o = rid & 255;
    const float e  = 1.f + eps[h];
    const float al = alpha[h];
    const float* wr = W1 + (size_t)o * 1024;
    u16* dst = ws + O_W1C + (size_t)rid * 768;
    dst[t]       = f2bf(e * wr[t] + wr[512 + t]);
    dst[256 + t] = f2bf(al * wr[256 + t]);
    dst[512 + t] = f2bf(wr[768 + t]);
  }
}

// ---------------- K2/K2b: dual GEMM sharing A (XCD-grouped block decode) ----------------
// MODE 0: g=x@Wg^T, u=x@Wu^T, h=silu(g)*u -> comb[:, :, 0:256] and hB (chunked). Grid 512 1-D.
// MODE 1: Q=h@Wq^T -> Qb; K=h@Wk^T -> Kc chunked. Grid 512 1-D, head-grouped per XCD.
template <int MODE>
__global__ __launch_bounds__(256, 2) void k_dual(const u16* __restrict__ Ab,
                                                 const u16* __restrict__ B0b,
                                                 const u16* __restrict__ B1b,
                                                 u16* __restrict__ o0, u16* __restrict__ o1) {
  __shared__ u16 lA[4096], lB0[4096], lB1[4096];
  const int tid = threadIdx.x, lane = tid & 63, wid = tid >> 6;
  const int wm = wid >> 1, wn = wid & 1;
  int m0, nt, head;
  {
    const int bid = blockIdx.x, slot = bid & 7, j = bid >> 3;   // slot -> XCD
    if (MODE == 0) {
      nt   = slot * 4 + (j & 3);     // 4 B-panels per XCD (2 MB, L2-resident)
      m0   = (j >> 2) * 128;
      head = 0;
    } else {
      head = slot + 8 * (j >> 5);    // 2 heads per XCD
      const int rem = j & 31;
      nt   = rem & 1;
      m0   = (rem >> 1) * 128;
    }
  }

  const int K  = (MODE == 0) ? HID : D;
  const int sA = (MODE == 0) ? HID : 768;
  const int sB = (MODE == 0) ? HID : D;
  const u16* A  = (MODE == 0) ? (Ab + (size_t)m0 * HID)
                              : (Ab + ((size_t)head * S + m0) * 768);
  const u16* B0 = (MODE == 0) ? (B0b + (size_t)nt * 128 * HID)
                              : (B0b + (size_t)head * D * D + (size_t)nt * 128 * D);
  const u16* B1 = (MODE == 0) ? (B1b + (size_t)nt * 128 * HID)
                              : (B1b + (size_t)head * D * D + (size_t)nt * 128 * D);

  f32x4 a0[4][4], a1[4][4];
#pragma unroll
  for (int i = 0; i < 4; ++i)
#pragma unroll
    for (int j2 = 0; j2 < 4; ++j2) { a0[i][j2] = f32x4{0.f,0.f,0.f,0.f}; a1[i][j2] = f32x4{0.f,0.f,0.f,0.f}; }

  for (int k0 = 0; k0 < K; k0 += 32) {
    __syncthreads();
    stage_rm(A  + k0, sA, lA,  tid);
    stage_rm(B0 + k0, sB, lB0, tid);
    stage_rm(B1 + k0, sB, lB1, tid);
    __syncthreads();
    const int kp = lane >> 4, r = lane & 15;
    s16x8 af[4], b0f[4], b1f[4];
#pragma unroll
    for (int f = 0; f < 4; ++f) {
      af[f]  = ldfrag(lA,  kp, wm * 64 + f * 16 + r);
      b0f[f] = ldfrag(lB0, kp, wn * 64 + f * 16 + r);
      b1f[f] = ldfrag(lB1, kp, wn * 64 + f * 16 + r);
    }
#pragma unroll
    for (int fi = 0; fi < 4; ++fi)
#pragma unroll
      for (int fj = 0; fj < 4; ++fj) {
        a0[fi][fj] = __builtin_amdgcn_mfma_f32_16x16x32_bf16(af[fi], b0f[fj], a0[fi][fj], 0, 0, 0);
        a1[fi][fj] = __builtin_amdgcn_mfma_f32_16x16x32_bf16(af[fi], b1f[fj], a1[fi][fj], 0, 0, 0);
      }
  }

#pragma unroll
  for (int fi = 0; fi < 4; ++fi)
#pragma unroll
    for (int fj = 0; fj < 4; ++fj)
#pragma unroll
      for (int reg = 0; reg < 4; ++reg) {
        int row = m0 + wm * 64 + fi * 16 + ((lane >> 4) * 4 + reg);
        int cl  = wn * 64 + fj * 16 + (lane & 15);
        if (MODE == 0) {
          int col = nt * 128 + cl;
          float g = a0[fi][fj][reg], uu = a1[fi][fj][reg];
          float h = g / (1.f + __expf(-g)) * uu;   // silu(g)*u
          u16 hb = f2bf(h);
          int hh = col >> 8, d = col & 255;
          o0[((size_t)hh * S + row) * 768 + d] = hb;                               // comb h-part
          o1[(((size_t)hh * (S / 8) + (row >> 3)) * 256 + d) * 8 + (row & 7)] = hb; // hB chunked
        } else {
          int e = nt * 128 + cl;
          o0[((size_t)head * S + row) * D + e] = f2bf(a0[fi][fj][reg]);            // Q row-major
          o1[(((size_t)head * 32 + (e >> 3)) * S + row) * 8 + (e & 7)] = f2bf(a1[fi][fj][reg]); // Kc chunked
        }
      }
}

// ---------------- K3: fused flash attention (multiplicative adj mask) + sum_agg ----------------
// Round-10/12 core: double-buffered staging, counted vmcnt(10), head->XCD-grouped grid,
// non-temporal adjacency loads.
__global__ __launch_bounds__(256, 2) void k_attn(const float* __restrict__ adj,
                                                 const u16* __restrict__ Qb,
                                                 const u16* __restrict__ Kc,
                                                 const u16* __restrict__ hB,
                                                 u16* __restrict__ comb) {
  __shared__ u16 lK[2][1024 * 8];   // [e8:32][t:32] 16B chunks, 16KB each
  __shared__ u16 lH[2][1024 * 8];   // [t8:4][d:256] 16B chunks, 16KB each
  __shared__ u16 lAdj[2][64 * 36];  // [q:64][t:32 pad 36], 4.5KB each
  __shared__ u16 lP[4][16 * 36];    // per-wave P transpose, 4.5KB
  const int tid = threadIdx.x, lane = tid & 63, wid = tid >> 6;
  // head->XCD grouping: bid%8 selects a head-group slot; each XCD serves heads {s, s+8}
  const int bid  = blockIdx.x;
  const int slot = bid & 7;
  const int idx  = bid >> 3;          // 0..63
  const int head = slot + 8 * (idx >> 5);
  const int bx   = idx & 31;
  const int q0 = bx * 64 + wid * 16;
  const int l15 = lane & 15, l4 = lane >> 4;

  s16x8 q[8];
  {
    const u16* qr = Qb + ((size_t)head * S + q0 + l15) * D + l4 * 8;
#pragma unroll
    for (int ks = 0; ks < 8; ++ks) q[ks] = *(const s16x8*)(qr + ks * 32);
  }
  f32x4 accO[16], accS[16];
#pragma unroll
  for (int i = 0; i < 16; ++i) { accO[i] = f32x4{0.f,0.f,0.f,0.f}; accS[i] = f32x4{0.f,0.f,0.f,0.f}; }
  float m_r[4] = {-1e30f, -1e30f, -1e30f, -1e30f};
  float l_r[4] = {0.f, 0.f, 0.f, 0.f};   // per-lane partial denominators

  const float* adjB = adj + ((size_t)head * S + bx * 64) * S;
  const int arow = tid >> 3;          // 0..31
  const int acol = (tid & 7) * 4;     // 0,4,..,28

  // prologue: stage tile 0 (K,H) into buf0 + prefetch adjacency tile 0 to regs
#pragma unroll
  for (int i = 0; i < 4; ++i) {
    int c = i * 256 + tid;
    gload16(Kc + ((size_t)(head * 32 + (c >> 5)) * S + (c & 31)) * 8,
            &lK[0][(size_t)(i * 256 + wid * 64) * 8]);
  }
#pragma unroll
  for (int i = 0; i < 4; ++i) {
    int c = i * 256 + tid;
    gload16(hB + ((size_t)(head * (S / 8) + (c >> 8)) * 256 + (c & 255)) * 8,
            &lH[0][(size_t)(i * 256 + wid * 64) * 8]);
  }
  f32x4 av0 = ntload(adjB + (size_t)arow * S + acol);
  f32x4 av1 = ntload(adjB + (size_t)(arow + 32) * S + acol);

  auto TILE = [&](int t0, int cur) {
    const int t1 = (t0 + 32 < S) ? t0 + 32 : t0;   // clamp: constant vmem count every iter
    // --- issue stage of tile t+1 into buf[cur^1] (8 gload_lds) ---
#pragma unroll
    for (int i = 0; i < 4; ++i) {
      int c = i * 256 + tid;
      gload16(Kc + ((size_t)(head * 32 + (c >> 5)) * S + t1 + (c & 31)) * 8,
              &lK[cur ^ 1][(size_t)(i * 256 + wid * 64) * 8]);
    }
#pragma unroll
    for (int i = 0; i < 4; ++i) {
      int c = i * 256 + tid;
      gload16(hB + ((size_t)(head * (S / 8) + (t1 >> 3) + (c >> 8)) * 256 + (c & 255)) * 8,
              &lH[cur ^ 1][(size_t)(i * 256 + wid * 64) * 8]);
    }
    // --- prefetch adjacency tile t+1 to regs (2 non-temporal loads) ---
    f32x4 nv0 = ntload(adjB + (size_t)arow * S + t1 + acol);
    f32x4 nv1 = ntload(adjB + (size_t)(arow + 32) * S + t1 + acol);
    // --- write adjacency tile t (regs) to lAdj[cur] as bf16 ---
    {
      s16x4 w;
      w[0] = (short)f2bf(av0[0]); w[1] = (short)f2bf(av0[1]);
      w[2] = (short)f2bf(av0[2]); w[3] = (short)f2bf(av0[3]);
      *(s16x4*)(&lAdj[cur][(size_t)arow * 36 + acol]) = w;
      w[0] = (short)f2bf(av1[0]); w[1] = (short)f2bf(av1[1]);
      w[2] = (short)f2bf(av1[2]); w[3] = (short)f2bf(av1[3]);
      *(s16x4*)(&lAdj[cur][(size_t)(arow + 32) * 36 + acol]) = w;
    }
    // wait: tile t's 10 vmem ops done (t+1's 10 stay in flight); lAdj writes done.
    asm volatile("s_waitcnt vmcnt(10) lgkmcnt(0)" ::: "memory");
    __builtin_amdgcn_s_barrier();
    __builtin_amdgcn_sched_barrier(0);

    const u16* lKc = &lK[cur][0];
    const u16* lHc = &lH[cur][0];
    const u16* lAc = &lAdj[cur][0];

    // QK^T (16 MFMA, 4 independent accumulator chains of depth 4)
    f32x4 scA[2], scB[2];
    scA[0] = f32x4{0.f,0.f,0.f,0.f}; scA[1] = f32x4{0.f,0.f,0.f,0.f};
    scB[0] = f32x4{0.f,0.f,0.f,0.f}; scB[1] = f32x4{0.f,0.f,0.f,0.f};
#pragma unroll
    for (int ks = 0; ks < 4; ++ks)
#pragma unroll
      for (int fj = 0; fj < 2; ++fj) {
        s16x8 b0 = *(const s16x8*)(lKc + ((size_t)(ks * 4 + l4) * 32 + fj * 16 + l15) * 8);
        s16x8 b1 = *(const s16x8*)(lKc + ((size_t)((ks + 4) * 4 + l4) * 32 + fj * 16 + l15) * 8);
        scA[fj] = __builtin_amdgcn_mfma_f32_16x16x32_bf16(q[ks], b0, scA[fj], 0, 0, 0);
        scB[fj] = __builtin_amdgcn_mfma_f32_16x16x32_bf16(q[ks + 4], b1, scB[fj], 0, 0, 0);
      }

    // mask values from lAdj (D-layout scalar reads)
    float av[2][4];
#pragma unroll
    for (int fj = 0; fj < 2; ++fj)
#pragma unroll
      for (int reg = 0; reg < 4; ++reg)
        av[fj][reg] = bf2f(lAc[(size_t)(wid * 16 + l4 * 4 + reg) * 36 + fj * 16 + l15]);

    float sf[2][4];
#pragma unroll
    for (int fj = 0; fj < 2; ++fj)
#pragma unroll
      for (int reg = 0; reg < 4; ++reg)
        sf[fj][reg] = (scA[fj][reg] + scB[fj][reg]) * 0.0625f;

    // defer-max: only reduce + rescale when some score exceeds m_r + 8
    bool chg = false;
    float lmax[4];
#pragma unroll
    for (int reg = 0; reg < 4; ++reg) {
      lmax[reg] = fmaxf(sf[0][reg], sf[1][reg]);
      chg |= (lmax[reg] > m_r[reg] + 8.f);
    }
    if (__any((int)chg)) {
      float scl[4];
#pragma unroll
      for (int reg = 0; reg < 4; ++reg) {
        float m = lmax[reg];
#pragma unroll
        for (int off = 1; off < 16; off <<= 1) m = fmaxf(m, __shfl_xor(m, off));
        float mn = fmaxf(m_r[reg], m);
        scl[reg] = __expf(m_r[reg] - mn);
        m_r[reg] = mn;
        l_r[reg] *= scl[reg];
      }
#pragma unroll
      for (int nf = 0; nf < 16; ++nf) {
        f32x4 t = accO[nf];
        t[0] *= scl[0]; t[1] *= scl[1]; t[2] *= scl[2]; t[3] *= scl[3];
        accO[nf] = t;
      }
    }
    u16 pb[2][4];
#pragma unroll
    for (int fj = 0; fj < 2; ++fj)
#pragma unroll
      for (int reg = 0; reg < 4; ++reg) {
        float p = (av[fj][reg] + 1e-9f) * exp2f((sf[fj][reg] - m_r[reg]) * 1.44269504f);
        l_r[reg] += p;                       // per-lane partial denominator
        pb[fj][reg] = f2bf(p);
      }

    // P: D-layout -> A-frag layout via wave-private LDS
    u16* pl = &lP[wid][0];
#pragma unroll
    for (int fj = 0; fj < 2; ++fj)
#pragma unroll
      for (int reg = 0; reg < 4; ++reg)
        pl[(size_t)(l4 * 4 + reg) * 36 + fj * 16 + l15] = pb[fj][reg];
    asm volatile("s_waitcnt lgkmcnt(0)" ::: "memory");
    __builtin_amdgcn_sched_barrier(0);

    s16x8 pa, aa;
    {
      s16x4 plo = *(const s16x4*)(pl + (size_t)l15 * 36 + l4 * 8);
      s16x4 phi = *(const s16x4*)(pl + (size_t)l15 * 36 + l4 * 8 + 4);
      pa[0] = plo[0]; pa[1] = plo[1]; pa[2] = plo[2]; pa[3] = plo[3];
      pa[4] = phi[0]; pa[5] = phi[1]; pa[6] = phi[2]; pa[7] = phi[3];
      s16x4 alo = *(const s16x4*)(lAc + (size_t)(wid * 16 + l15) * 36 + l4 * 8);
      s16x4 ahi = *(const s16x4*)(lAc + (size_t)(wid * 16 + l15) * 36 + l4 * 8 + 4);
      aa[0] = alo[0]; aa[1] = alo[1]; aa[2] = alo[2]; aa[3] = alo[3];
      aa[4] = ahi[0]; aa[5] = ahi[1]; aa[6] = ahi[2]; aa[7] = ahi[3];
    }
    // PV + sum_agg (32 MFMA) sharing lH fragment reads
#pragma unroll
    for (int nf = 0; nf < 16; ++nf) {
      s16x8 hb = *(const s16x8*)(lHc + ((size_t)l4 * 256 + nf * 16 + l15) * 8);
      accO[nf] = __builtin_amdgcn_mfma_f32_16x16x32_bf16(pa, hb, accO[nf], 0, 0, 0);
      accS[nf] = __builtin_amdgcn_mfma_f32_16x16x32_bf16(aa, hb, accS[nf], 0, 0, 0);
    }

    av0 = nv0; av1 = nv1;

    // end barrier: all waves done reading buf[cur] before next tile stages into it.
    __builtin_amdgcn_sched_barrier(0);
    __builtin_amdgcn_s_barrier();
  };

  for (int t0 = 0; t0 < S; t0 += 64) {
    TILE(t0, 0);
    TILE(t0 + 32, 1);
  }

  // drain in-flight gload_lds before workgroup can exit
  asm volatile("s_waitcnt vmcnt(0)" ::: "memory");

  // epilogue: reduce per-lane denominators across the 16 lanes of each q-row
#pragma unroll
  for (int reg = 0; reg < 4; ++reg) {
#pragma unroll
    for (int off = 1; off < 16; off <<= 1) l_r[reg] += __shfl_xor(l_r[reg], off);
  }
  float inv[4];
#pragma unroll
  for (int reg = 0; reg < 4; ++reg) inv[reg] = 1.f / l_r[reg];
#pragma unroll
  for (int nf = 0; nf < 16; ++nf)
#pragma unroll
    for (int reg = 0; reg < 4; ++reg) {
      size_t rb = ((size_t)head * S + q0 + l4 * 4 + reg) * 768;
      comb[rb + 512 + nf * 16 + l15] = f2bf(accO[nf][reg] * inv[reg]);
      comb[rb + 256 + nf * 16 + l15] = f2bf(accS[nf][reg]);
    }
}

// ---------------- K4/K5/K6: single-B GEMMs (XCD-grouped decodes) ----------------
// MODE 0: u = silu(comb @ W1cat^T) per head    -> oU[s][head*256+e] (BN=128, 1-D 512, head-grouped)
// MODE 3: Wfold_h = Wd_h @ W2 (B = W2^T)       -> oU[o][head*256+c] (BN=128, 3-D grid)
// MODE 2: out = u @ Wfold^T                    -> oF[s][1024] f32   (BN=64, 1-D 256, nt-grouped)
template <int MODE>
__global__ __launch_bounds__(256, 2) void k_gemm(const u16* __restrict__ Ab,
                                                 const u16* __restrict__ Bb,
                                                 u16* __restrict__ oU, float* __restrict__ oF) {
  constexpr int BN = (MODE == 2) ? 64 : 128;
  constexpr int FJ = BN / 32;            // frags per wave in N
  __shared__ u16 lA[4096], lB[BN * 32];
  const int tid = threadIdx.x, lane = tid & 63, wid = tid >> 6;
  const int wm = wid >> 1, wn = wid & 1;
  int m0, nt, head;
  if constexpr (MODE == 0) {
    const int bid = blockIdx.x, slot = bid & 7, j = bid >> 3;
    head = slot + 8 * (j >> 5);          // 2 heads per XCD (B = 768KB, L2-resident)
    const int rem = j & 31;
    nt   = rem & 1;
    m0   = (rem >> 1) * 128;
  } else if constexpr (MODE == 2) {
    const int bid = blockIdx.x, slot = bid & 7, j = bid >> 3;
    nt   = slot * 2 + (j & 1);           // 2 B-panels per XCD (1 MB, L2-resident)
    m0   = (j >> 1) * 128;
    head = 0;
  } else {
    m0 = blockIdx.x * 128; nt = blockIdx.y; head = blockIdx.z;
  }

  constexpr int K  = (MODE == 0) ? 768 : (MODE == 2) ? INTER : D;
  constexpr int sA = (MODE == 3) ? INTER : K;
  constexpr int sB = K;
  const u16* A = (MODE == 0) ? Ab + ((size_t)head * S + m0) * 768
               : (MODE == 2) ? Ab + (size_t)m0 * INTER
                             : Ab + (size_t)m0 * INTER + head * D;
  const u16* B = (MODE == 0) ? Bb + ((size_t)head * D + nt * 128) * 768
                             : Bb + (size_t)nt * BN * sB;

  f32x4 acc[4][FJ];
#pragma unroll
  for (int i = 0; i < 4; ++i)
#pragma unroll
    for (int j = 0; j < FJ; ++j) acc[i][j] = f32x4{0.f,0.f,0.f,0.f};

  for (int k0 = 0; k0 < K; k0 += 32) {
    __syncthreads();
    stage_rm(A + k0, sA, lA, tid);
    if constexpr (BN == 128) stage_rm(B + k0, sB, lB, tid);
    else                     stage_rm64(B + k0, sB, lB, tid);
    __syncthreads();
    const int kp = lane >> 4, r = lane & 15;
    s16x8 af[4], bf[FJ];
#pragma unroll
    for (int f = 0; f < 4; ++f) af[f] = ldfrag(lA, kp, wm * 64 + f * 16 + r);
#pragma unroll
    for (int f = 0; f < FJ; ++f) {
      if constexpr (BN == 128) bf[f] = ldfrag(lB, kp, wn * 64 + f * 16 + r);
      else                     bf[f] = ldfrag64(lB, kp, wn * 32 + f * 16 + r);
    }
#pragma unroll
    for (int fi = 0; fi < 4; ++fi)
#pragma unroll
      for (int fj = 0; fj < FJ; ++fj)
        acc[fi][fj] = __builtin_amdgcn_mfma_f32_16x16x32_bf16(af[fi], bf[fj], acc[fi][fj], 0, 0, 0);
  }

#pragma unroll
  for (int fi = 0; fi < 4; ++fi)
#pragma unroll
    for (int fj = 0; fj < FJ; ++fj)
#pragma unroll
      for (int reg = 0; reg < 4; ++reg) {
        int row = m0 + wm * 64 + fi * 16 + ((lane >> 4) * 4 + reg);
        int cn = nt * BN + wn * (BN / 2) + fj * 16 + (lane & 15);
        float v = acc[fi][fj][reg];
        if (MODE == 0) {
          v = v / (1.f + __expf(-v));
          oU[(size_t)row * INTER + head * D + cn] = f2bf(v);
        } else if (MODE == 3) {
          oU[(size_t)row * INTER + head * D + cn] = f2bf(v);
        } else {
          oF[(size_t)row * HID + cn] = v;
        }
      }
}

// ---------------- launch ----------------
extern "C" void kernel_launch(void* const* d_in, const int* in_sizes, int n_in,
                              void* d_out, int out_size, void* d_ws, size_t ws_size,
                              hipStream_t stream) {
  const float* x     = (const float*)d_in[0];
  const float* adj   = (const float*)d_in[1];
  const float* Wg    = (const float*)d_in[2];
  const float* Wu    = (const float*)d_in[3];
  const float* Wd    = (const float*)d_in[4];
  const float* eps   = (const float*)d_in[5];
  const float* alpha = (const float*)d_in[6];
  const float* Wq    = (const float*)d_in[7];
  const float* Wk    = (const float*)d_in[8];
  const float* W1    = (const float*)d_in[9];
  const float* W2    = (const float*)d_in[10];
  u16* ws = (u16*)d_ws;

  k_convert<<<dim3(4096), dim3(256), 0, stream>>>(x, Wg, Wu, Wd, Wq, Wk, W1, W2, eps, alpha, ws);
  // 1-D grids, XCD-grouped decode inside kernels
  k_dual<0><<<dim3(512), dim3(256), 0, stream>>>(ws + O_XB, ws + O_WG, ws + O_WU,
                                                 ws + O_COMB, ws + O_HB);
  k_dual<1><<<dim3(512), dim3(256), 0, stream>>>(ws + O_COMB, ws + O_WQ, ws + O_WK,
                                                 ws + O_QB, ws + O_KC);
  k_attn<<<dim3(512), dim3(256), 0, stream>>>(adj, ws + O_QB, ws + O_KC, ws + O_HB, ws + O_COMB);
  // Wfold = Wd_h @ W2 (O_KC is free after k_attn)
  k_gemm<3><<<dim3(8, 2, 16), dim3(256), 0, stream>>>(ws + O_WD, ws + O_W2, ws + O_KC, nullptr);
  // u = silu(comb @ W1cat^T), head-grouped 1-D grid
  k_gemm<0><<<dim3(512), dim3(256), 0, stream>>>(ws + O_COMB, ws + O_W1C, ws + O_QB, nullptr);
  // out = u @ Wfold^T (BN=64, nt-grouped 1-D grid)
  k_gemm<2><<<dim3(256), dim3(256), 0, stream>>>(ws + O_QB, ws + O_KC, nullptr, (float*)d_out);
}